// Round 7
// baseline (625.222 us; speedup 1.0000x reference)
//
#include <hip/hip_runtime.h>
#include <hip/hip_bf16.h>

#define T_ 4
#define B_ 4
#define N_ 16384
#define KALL_ 4
#define F_ 16384
#define ORD_ 3
#define DIN_ 4
#define H_ 64
#define H3_ 192
#define DE_ 4
#define STR 72   // padded bf16 leading-dim for MFMA A/B LDS tiles (144 B rows, 16B-aligned)

typedef __attribute__((ext_vector_type(8))) short s16x8;
typedef __attribute__((ext_vector_type(4))) float f32x4;

static __device__ __forceinline__ float b2f(unsigned short u) {
  union { unsigned u; float f; } x; x.u = ((unsigned)u) << 16; return x.f;
}
static __device__ __forceinline__ unsigned short f2b(float f) {
  __hip_bfloat16 h = __float2bfloat16(f);  // RNE
  union { __hip_bfloat16 h; unsigned short u; } x; x.h = h; return x.u;
}

// dones encoding sniffer: word mode (int32 0/1 or f32 0.0/1.0) vs packed
// uint8 bools. Under byte mode, words 4..15 read into following data
// (values almost surely not all in {0,1,0x3F800000}).
static __device__ __forceinline__ bool decode_done(const int* __restrict__ dn, int tb) {
  bool word = true;
#pragma unroll
  for (int i = 0; i < 16; ++i) {
    int v = dn[i];
    if (v != 0 && v != 1 && v != 0x3F800000) word = false;
  }
  if (word) return dn[tb] != 0;
  return ((const unsigned char*)dn)[tb] != 0;
}

// ---------------------------------------------------------------------------
// Kernel 1: ONE GRU step t. Block = 256 thr (4 waves) owns 64 nodes of one b.
// f32 inputs; carry chains through the f32 h_fin output slot (full precision).
// gh via MFMA 16x16x32 bf16 (internal bf16 only).
// ---------------------------------------------------------------------------
__global__ __launch_bounds__(256) void k_gru_step(
    const int t,
    const float* __restrict__ h0,        // [B,N,H] f32, carry source at t==0
    const float* __restrict__ x,         // [T,B,N,DIN] f32
    const int* __restrict__ dones,
    const float* __restrict__ Wi,        // [DIN,3H]
    const float* __restrict__ bi,        // [3H]
    const float* __restrict__ Wh,        // [H,3H]
    const float* __restrict__ bhn,       // [H]
    float* __restrict__ hcur)            // [B,N,H] f32 = h_fin slot; in/out carry
{
  __shared__ short whT[H3_ * STR];   // whT[col][k] = Wh[k][col]  (B-operand layout)
  __shared__ short carry[H_ * STR];  // carry[node][k] bf16       (A-operand layout)
  __shared__ float carryF[H_ * 65];  // carry[node][k] f32        (epilogue, padded)
  __shared__ float xt[256];

  const int tid = threadIdx.x;
  const int lane = tid & 63;
  const int w = tid >> 6;
  const int c15 = lane & 15;
  const int hi4 = lane >> 4;
  const int bid = blockIdx.x;
  const int b = bid >> 8;                 // 256 blocks per b
  const int nbase = (bid & 255) * 64;

  for (int i = tid; i < H_ * H3_; i += 256) {
    int k = i / H3_;
    int c = i - k * H3_;
    whT[c * STR + k] = (short)f2b(Wh[i]);
  }
  const bool reset = decode_done(dones, t * B_ + b);
  for (int i = tid; i < H_ * H_; i += 256) {
    int r = i >> 6, k = i & 63;
    float v;
    if (reset) v = 0.f;
    else if (t == 0) v = h0[(b * N_ + nbase + r) * H_ + k];
    else v = hcur[(b * N_ + nbase + r) * H_ + k];
    carryF[r * 65 + k] = v;
    carry[r * STR + k] = (short)f2b(v);
  }
  xt[tid] = x[((t * B_ + b) * N_ + nbase + (tid >> 2)) * DIN_ + (tid & 3)];

  // per-lane register slices of Wi/bi/bhn for the gate epilogue
  float wir[3][4][4], bir[3][4], bhnr[4];
#pragma unroll
  for (int cg = 0; cg < 4; ++cg) {
    int hc = 16 * cg + c15;
    bhnr[cg] = bhn[hc];
#pragma unroll
    for (int g = 0; g < 3; ++g) {
      bir[g][cg] = bi[g * 64 + hc];
#pragma unroll
      for (int kk = 0; kk < 4; ++kk)
        wir[g][cg][kk] = Wi[kk * H3_ + g * 64 + hc];
    }
  }
  __syncthreads();

  f32x4 acc[12];
#pragma unroll
  for (int ct = 0; ct < 12; ++ct) acc[ct] = (f32x4){0.f, 0.f, 0.f, 0.f};
  const int rowA = 16 * w + c15;
#pragma unroll
  for (int ks = 0; ks < 2; ++ks) {
    const int kb = ks * 32 + hi4 * 8;
    s16x8 af = *(const s16x8*)&carry[rowA * STR + kb];
#pragma unroll
    for (int ct = 0; ct < 12; ++ct) {
      s16x8 bfr = *(const s16x8*)&whT[(16 * ct + c15) * STR + kb];
      acc[ct] = __builtin_amdgcn_mfma_f32_16x16x32_bf16(af, bfr, acc[ct], 0, 0, 0);
    }
  }
  // gate epilogue: lane holds D[row=16w+hi4*4+r][col=16ct+c15]
#pragma unroll
  for (int r = 0; r < 4; ++r) {
    const int row = 16 * w + hi4 * 4 + r;
    const int node = nbase + row;
    const float x0 = xt[row * 4 + 0], x1 = xt[row * 4 + 1],
                x2 = xt[row * 4 + 2], x3 = xt[row * 4 + 3];
#pragma unroll
    for (int cg = 0; cg < 4; ++cg) {
      const int hc = 16 * cg + c15;
      float gr = bir[0][cg] + x0 * wir[0][cg][0] + x1 * wir[0][cg][1]
               + x2 * wir[0][cg][2] + x3 * wir[0][cg][3] + acc[cg][r];
      float gz = bir[1][cg] + x0 * wir[1][cg][0] + x1 * wir[1][cg][1]
               + x2 * wir[1][cg][2] + x3 * wir[1][cg][3] + acc[4 + cg][r];
      float gn = bir[2][cg] + x0 * wir[2][cg][0] + x1 * wir[2][cg][1]
               + x2 * wir[2][cg][2] + x3 * wir[2][cg][3];
      float rg = 1.f / (1.f + __expf(-gr));
      float zg = 1.f / (1.f + __expf(-gz));
      float cold = carryF[row * 65 + hc];
      float ng = tanhf(gn + rg * (acc[8 + cg][r] + bhnr[cg]));
      float nc = (1.f - zg) * ng + zg * cold;
      hcur[(b * N_ + node) * H_ + hc] = nc;   // f32 out; carry for t+1; h_fin at t=3
    }
  }
}

// ---------------------------------------------------------------------------
// Kernel 2: fused factor attention for ONE timestep. Block processes 4 chunks
// of 16 factors (48 gathered rows each). f32 weights, bf16 staged for MFMA.
// ---------------------------------------------------------------------------
__global__ __launch_bounds__(256) void k_attn(
    const float* __restrict__ h,              // [B,N,H] f32 (this t)
    const int* __restrict__ indices,
    const float* __restrict__ Wq, const float* __restrict__ bq,
    const float* __restrict__ Wk, const float* __restrict__ bk,
    const float* __restrict__ Wv, const float* __restrict__ bv,
    const float* __restrict__ Wo, const float* __restrict__ bo,
    float* __restrict__ y)                    // [B,N,H] f32, pre-zeroed
{
  __shared__ short buf[48 * STR];      // g rows, later reused for o rows
  __shared__ short wT[4][64 * STR];    // q,k,v: [nd][h]; o: [h][nd]
  __shared__ short qkv[3][48 * 64];
  __shared__ float biasf[4][64];
  __shared__ int idxs[48];

  const int tid = threadIdx.x;
  const int lane = tid & 63;
  const int w = tid >> 6;
  const int c15 = lane & 15;
  const int hi4 = lane >> 4;
  const int bid = blockIdx.x;

  for (int i = tid; i < 3 * 4096; i += 256) {
    int m = i >> 12, j = i & 4095;
    int hrow = j >> 6, nd = j & 63;
    const float* Wm = (m == 0) ? Wq : (m == 1) ? Wk : Wv;
    wT[m][nd * STR + hrow] = (short)f2b(Wm[j]);
  }
  for (int i = tid; i < 4096; i += 256) {
    int nd = i >> 6, hcol = i & 63;
    wT[3][hcol * STR + nd] = (short)f2b(Wo[i]);
  }
  if (tid < 64) {
    biasf[0][tid] = bq[tid];
    biasf[1][tid] = bk[tid];
    biasf[2][tid] = bv[tid];
    biasf[3][tid] = bo[tid];
  }

  for (int c = 0; c < 4; ++c) {
    const int chunk = bid * 4 + c;          // 4096 chunks per t
    const int b = chunk >> 10;              // batch
    const int fbase3 = (chunk & 1023) * 48;

    __syncthreads();  // protect buf/idxs/qkv reuse across chunks (and staging, c=0)
    if (tid < 48) idxs[tid] = indices[fbase3 + tid];
    __syncthreads();

    for (int i = tid; i < 48 * 64; i += 256) {
      int row = i >> 6, hh = i & 63;
      buf[row * STR + hh] = (short)f2b(h[(b * N_ + idxs[row]) * H_ + hh]);
    }
    __syncthreads();

    // Q/K/V projections: 36 tiles (3 mats x 3 row-tiles x 4 col-tiles)
    for (int tn = w; tn < 36; tn += 4) {
      int m = tn / 12, r12 = tn - m * 12, rt = r12 >> 2, ct = r12 & 3;
      f32x4 acc = (f32x4){0.f, 0.f, 0.f, 0.f};
#pragma unroll
      for (int ks = 0; ks < 2; ++ks) {
        int kb = ks * 32 + hi4 * 8;
        s16x8 af = *(const s16x8*)&buf[(16 * rt + c15) * STR + kb];
        s16x8 bfr = *(const s16x8*)&wT[m][(16 * ct + c15) * STR + kb];
        acc = __builtin_amdgcn_mfma_f32_16x16x32_bf16(af, bfr, acc, 0, 0, 0);
      }
      int col = 16 * ct + c15;
      float bias = biasf[m][col];
      float scl = (m == 0) ? 0.25f : 1.f;   // 1/sqrt(HD) folded into q (after bias)
#pragma unroll
      for (int r = 0; r < 4; ++r) {
        int row = 16 * rt + hi4 * 4 + r;
        qkv[m][row * 64 + col] = (short)f2b((acc[r] + bias) * scl);
      }
    }
    __syncthreads();

    // per-(factor, head, qi) softmax + PV
    if (tid < 192) {
      int f = tid / 12, rem = tid - f * 12, head = rem / 3, qi = rem - head * 3;
      int rbase = f * 3;
      int cbase = head * 16;
      float q[16];
#pragma unroll
      for (int d = 0; d < 16; ++d)
        q[d] = b2f((unsigned short)qkv[0][(rbase + qi) * 64 + cbase + d]);
      float s[3];
#pragma unroll
      for (int ki = 0; ki < 3; ++ki) {
        float a = 0.f;
#pragma unroll
        for (int d = 0; d < 16; ++d)
          a += q[d] * b2f((unsigned short)qkv[1][(rbase + ki) * 64 + cbase + d]);
        s[ki] = a;
      }
      float mx = fmaxf(s[0], fmaxf(s[1], s[2]));
      float e0 = __expf(s[0] - mx), e1 = __expf(s[1] - mx), e2 = __expf(s[2] - mx);
      float inv = 1.f / (e0 + e1 + e2);
      e0 *= inv; e1 *= inv; e2 *= inv;
#pragma unroll
      for (int d = 0; d < 16; ++d) {
        float o = e0 * b2f((unsigned short)qkv[2][(rbase + 0) * 64 + cbase + d])
                + e1 * b2f((unsigned short)qkv[2][(rbase + 1) * 64 + cbase + d])
                + e2 * b2f((unsigned short)qkv[2][(rbase + 2) * 64 + cbase + d]);
        buf[(rbase + qi) * STR + cbase + d] = (short)f2b(o);
      }
    }
    __syncthreads();

    // a = o @ Wo + bo, scattered via f32 atomics into per-t y
    for (int tn = w; tn < 12; tn += 4) {
      int rt = tn >> 2, ct = tn & 3;
      f32x4 acc = (f32x4){0.f, 0.f, 0.f, 0.f};
#pragma unroll
      for (int ks = 0; ks < 2; ++ks) {
        int kb = ks * 32 + hi4 * 8;
        s16x8 af = *(const s16x8*)&buf[(16 * rt + c15) * STR + kb];
        s16x8 bfr = *(const s16x8*)&wT[3][(16 * ct + c15) * STR + kb];
        acc = __builtin_amdgcn_mfma_f32_16x16x32_bf16(af, bfr, acc, 0, 0, 0);
      }
      int col = 16 * ct + c15;
      float bias = biasf[3][col];
#pragma unroll
      for (int r = 0; r < 4; ++r) {
        int row = 16 * rt + hi4 * 4 + r;
        atomicAdd(&y[(b * N_ + idxs[row]) * H_ + col], acc[r] + bias);
      }
    }
  }
}

// ---------------------------------------------------------------------------
// Kernel 3: ONE timestep: y/=nnz; logit = relu(z@W1[68x64]+b1)@W2[64]+b2 via
// MFMA; y_global partial sums into yg. Block = 64 nodes, grid 1024 = 4b x 256.
// ---------------------------------------------------------------------------
__global__ __launch_bounds__(256) void k_head(
    const int t,
    const float* __restrict__ y,              // [B,N,H] f32 (this t)
    const float* __restrict__ nnz,            // [N] f32
    const float* __restrict__ extra,          // [T,B,KALL,DE] f32
    const float* __restrict__ W1, const float* __restrict__ b1,
    const float* __restrict__ W2, const float* __restrict__ b2,
    float* __restrict__ yg,                   // [T*B, KALL, H] f32, pre-zeroed
    float* __restrict__ logit)                // [T,B,N] f32 (full tensor)
{
  __shared__ short w1T[64 * STR];   // w1T[col][k] = W1[k][col] (first 64 rows of W1)
  __shared__ short arow[64 * STR];  // arow[node][h] = y/nnz (bf16)
  __shared__ float hEx[64];         // b1 + extra @ W1[64:68]
  __shared__ float w2s[64];
  __shared__ float red[4][64];

  const int tid = threadIdx.x;
  const int lane = tid & 63;
  const int w = tid >> 6;
  const int c15 = lane & 15;
  const int hi4 = lane >> 4;
  const int bid = blockIdx.x;
  const int b = bid >> 8;              // 256 blocks per b
  const int tb = t * B_ + b;
  const int nbase = (bid & 255) * 64;  // 64 nodes, fully inside one kall group
  const int kall = nbase >> 12;

  for (int i = tid; i < 4096; i += 256) {
    int k = i >> 6, col = i & 63;
    w1T[col * STR + k] = (short)f2b(W1[i]);
  }
  if (tid < 64) {
    float s = b1[tid];
#pragma unroll
    for (int e = 0; e < 4; ++e)
      s += extra[(tb * KALL_ + kall) * DE_ + e] * W1[(64 + e) * 64 + tid];
    hEx[tid] = s;
    w2s[tid] = W2[tid];
  }
  float accp = 0.f;
  for (int i = tid; i < 4096; i += 256) {
    int r = i >> 6, hcol = i & 63;   // hcol == tid&63, constant per thread
    int node = nbase + r;
    float val = y[(b * N_ + node) * H_ + hcol] / nnz[node];
    accp += val;
    arow[r * STR + hcol] = (short)f2b(val);
  }
  red[w][lane] = accp;
  __syncthreads();

  // wave w owns row-tile w (16 nodes), loops all 4 col-tiles
  f32x4 acc[4];
#pragma unroll
  for (int ct = 0; ct < 4; ++ct) acc[ct] = (f32x4){0.f, 0.f, 0.f, 0.f};
#pragma unroll
  for (int ks = 0; ks < 2; ++ks) {
    int kb = ks * 32 + hi4 * 8;
    s16x8 af = *(const s16x8*)&arow[(16 * w + c15) * STR + kb];
#pragma unroll
    for (int ct = 0; ct < 4; ++ct) {
      s16x8 bfr = *(const s16x8*)&w1T[(16 * ct + c15) * STR + kb];
      acc[ct] = __builtin_amdgcn_mfma_f32_16x16x32_bf16(af, bfr, acc[ct], 0, 0, 0);
    }
  }
  const float b2v = b2[0];
#pragma unroll
  for (int r = 0; r < 4; ++r) {
    float s = 0.f;
#pragma unroll
    for (int ct = 0; ct < 4; ++ct) {
      int col = 16 * ct + c15;
      s += fmaxf(acc[ct][r] + hEx[col], 0.f) * w2s[col];
    }
    s += __shfl_xor(s, 1, 64);
    s += __shfl_xor(s, 2, 64);
    s += __shfl_xor(s, 4, 64);
    s += __shfl_xor(s, 8, 64);
    if (c15 == 0)
      logit[tb * N_ + nbase + 16 * w + hi4 * 4 + r] = s + b2v;
  }
  if (tid < 64) {
    float sv = red[0][tid] + red[1][tid] + red[2][tid] + red[3][tid];
    atomicAdd(&yg[(tb * KALL_ + kall) * H_ + tid], sv);
  }
}

// ---------------------------------------------------------------------------
// Kernel 4: value head + h_global passthrough (f32 verbatim)
// ---------------------------------------------------------------------------
__global__ __launch_bounds__(256) void k_final(
    const float* __restrict__ yg,
    const float* __restrict__ extra,
    const float* __restrict__ Wv1, const float* __restrict__ bv1,
    const float* __restrict__ hg_in,
    float* __restrict__ value_out,
    float* __restrict__ hg_out)
{
  const int tid = threadIdx.x;
  if (tid < 16) {
    const float bv = bv1[0];
    float v = 0.f;
    for (int kall = 0; kall < 4; ++kall) {
      float s = bv;
      for (int hh = 0; hh < 64; ++hh)
        s += (yg[(tid * KALL_ + kall) * H_ + hh] * (1.f / 4096.f)) * Wv1[hh];
      for (int e = 0; e < 4; ++e)
        s += extra[(tid * KALL_ + kall) * DE_ + e] * Wv1[64 + e];
      v += s;
    }
    value_out[tid] = v;
  }
  for (int i = tid; i < 1024; i += 256) hg_out[i] = hg_in[i];
}

// ---------------------------------------------------------------------------
// Workspace layout (16.8 MB):
//   yg @ 0     : 16,384 B     f32 [T*B, KALL, H]
//   y  @ 16384 : 16,777,216 B f32 [B,N,H]  (per-t scatter buffer)
// GRU carry chains through the f32 h_fin output slot (d_out[0:4194304]).
// ---------------------------------------------------------------------------
extern "C" void kernel_launch(void* const* d_in, const int* in_sizes, int n_in,
                              void* d_out, int out_size, void* d_ws, size_t ws_size,
                              hipStream_t stream)
{
  (void)in_sizes; (void)n_in; (void)out_size; (void)ws_size;
  const float* h0    = (const float*)d_in[0];
  const float* hg    = (const float*)d_in[1];
  const float* x     = (const float*)d_in[2];
  const float* extra = (const float*)d_in[3];
  const int*   dn    = (const int*)d_in[4];
  const int*   idx   = (const int*)d_in[5];
  const float* nnz   = (const float*)d_in[6];
  const float* Wi    = (const float*)d_in[7];
  const float* bi    = (const float*)d_in[8];
  const float* Wh    = (const float*)d_in[9];
  const float* bhn   = (const float*)d_in[10];
  const float* Wq    = (const float*)d_in[11];
  const float* bq    = (const float*)d_in[12];
  const float* Wk    = (const float*)d_in[13];
  const float* bk    = (const float*)d_in[14];
  const float* Wv    = (const float*)d_in[15];
  const float* bv    = (const float*)d_in[16];
  const float* Wo    = (const float*)d_in[17];
  const float* bo    = (const float*)d_in[18];
  const float* W1    = (const float*)d_in[19];
  const float* b1    = (const float*)d_in[20];
  const float* W2    = (const float*)d_in[21];
  const float* b2    = (const float*)d_in[22];
  const float* Wv1   = (const float*)d_in[23];
  const float* bv1   = (const float*)d_in[24];

  float* out = (float*)d_out;
  float* out_hfin  = out;                 // [B,N,H]   f32  4194304
  float* out_hg    = out + 4194304;       // [B,K,DOUT]f32     1024
  float* out_logit = out + 4195328;       // [T,B,N]   f32   262144
  float* out_value = out + 4457472;       // [T,B]     f32       16

  char* wsb = (char*)d_ws;
  float* yg = (float*)wsb;                // 16 KB
  float* y  = (float*)(wsb + 16384);      // 16 MB f32

  hipMemsetAsync(yg, 0, 16384, stream);

  for (int t = 0; t < T_; ++t) {
    k_gru_step<<<1024, 256, 0, stream>>>(t, h0, x, dn, Wi, bi, Wh, bhn, out_hfin);
    hipMemsetAsync(y, 0, 16777216, stream);
    k_attn<<<1024, 256, 0, stream>>>(out_hfin, idx, Wq, bq, Wk, bk, Wv, bv, Wo, bo, y);
    k_head<<<1024, 256, 0, stream>>>(t, y, nnz, extra, W1, b1, W2, b2, yg, out_logit);
  }
  k_final<<<1, 256, 0, stream>>>(yg, extra, Wv1, bv1, hg, out_value, out_hg);
}

// Round 8
// 382.155 us; speedup vs baseline: 1.6360x; 1.6360x over previous
//
#include <hip/hip_runtime.h>
#include <hip/hip_bf16.h>

#define T_ 4
#define B_ 4
#define N_ 16384
#define KALL_ 4
#define F_ 16384
#define ORD_ 3
#define DIN_ 4
#define H_ 64
#define H3_ 192
#define DE_ 4
#define STR 72   // padded bf16 leading-dim for MFMA A/B LDS tiles (144 B rows, 16B-aligned)

typedef __attribute__((ext_vector_type(8))) short s16x8;
typedef __attribute__((ext_vector_type(4))) float f32x4;

static __device__ __forceinline__ float b2f(unsigned short u) {
  union { unsigned u; float f; } x; x.u = ((unsigned)u) << 16; return x.f;
}
static __device__ __forceinline__ unsigned short f2b(float f) {
  __hip_bfloat16 h = __float2bfloat16(f);  // RNE
  union { __hip_bfloat16 h; unsigned short u; } x; x.h = h; return x.u;
}

// dones encoding sniffer (unchanged from the passing R7 kernel)
static __device__ __forceinline__ bool decode_done(const int* __restrict__ dn, int tb) {
  bool word = true;
#pragma unroll
  for (int i = 0; i < 16; ++i) {
    int v = dn[i];
    if (v != 0 && v != 1 && v != 0x3F800000) word = false;
  }
  if (word) return dn[tb] != 0;
  return ((const unsigned char*)dn)[tb] != 0;
}

// ---------------------------------------------------------------------------
// Kernel 1: GRU, ALL t in one launch. Block = 256 thr owns 64 nodes of one b.
// Wh staged once per block; carry lives in LDS (f32 master + bf16 A-frags).
// Emits hs bf16 [T,B,N,H] for attention and h_fin f32 at t=3.
// ---------------------------------------------------------------------------
__global__ __launch_bounds__(256) void k_gru(
    const float* __restrict__ h0,
    const float* __restrict__ x,
    const int* __restrict__ dones,
    const float* __restrict__ Wi,
    const float* __restrict__ bi,
    const float* __restrict__ Wh,
    const float* __restrict__ bhn,
    unsigned short* __restrict__ hs,     // [T*B,N,H] bf16
    float* __restrict__ hfin)            // [B,N,H] f32
{
  __shared__ short whT[H3_ * STR];   // whT[col][k] = Wh[k][col] (B-operand layout)
  __shared__ float carryF[H_ * 65];  // f32 master carry, padded
  __shared__ short carry[H_ * STR];  // bf16 carry (A-operand layout)
  __shared__ float xt[256];

  const int tid = threadIdx.x;
  const int lane = tid & 63;
  const int w = tid >> 6;
  const int c15 = lane & 15;
  const int hi4 = lane >> 4;
  const int bid = blockIdx.x;
  const int b = bid >> 8;                 // 256 blocks per b
  const int nbase = (bid & 255) * 64;

  for (int i = tid; i < H_ * H3_; i += 256) {
    int k = i / H3_;
    int c = i - k * H3_;
    whT[c * STR + k] = (short)f2b(Wh[i]);
  }
  for (int i = tid; i < H_ * H_; i += 256) {
    int r = i >> 6, k = i & 63;
    float v = h0[(b * N_ + nbase + r) * H_ + k];
    carryF[r * 65 + k] = v;
    carry[r * STR + k] = (short)f2b(v);
  }

  float wir[3][4][4], bir[3][4], bhnr[4];
#pragma unroll
  for (int cg = 0; cg < 4; ++cg) {
    int hc = 16 * cg + c15;
    bhnr[cg] = bhn[hc];
#pragma unroll
    for (int g = 0; g < 3; ++g) {
      bir[g][cg] = bi[g * 64 + hc];
#pragma unroll
      for (int kk = 0; kk < 4; ++kk)
        wir[g][cg][kk] = Wi[kk * H3_ + g * 64 + hc];
    }
  }
  __syncthreads();

  for (int t = 0; t < T_; ++t) {
    xt[tid] = x[((t * B_ + b) * N_ + nbase + (tid >> 2)) * DIN_ + (tid & 3)];
    if (decode_done(dones, t * B_ + b)) {
      for (int i = tid; i < H_ * 65; i += 256) carryF[i] = 0.f;
      for (int i = tid; i < H_ * STR; i += 256) carry[i] = 0;
    }
    __syncthreads();

    f32x4 acc[12];
#pragma unroll
    for (int ct = 0; ct < 12; ++ct) acc[ct] = (f32x4){0.f, 0.f, 0.f, 0.f};
    const int rowA = 16 * w + c15;
#pragma unroll
    for (int ks = 0; ks < 2; ++ks) {
      const int kb = ks * 32 + hi4 * 8;
      s16x8 af = *(const s16x8*)&carry[rowA * STR + kb];
#pragma unroll
      for (int ct = 0; ct < 12; ++ct) {
        s16x8 bfr = *(const s16x8*)&whT[(16 * ct + c15) * STR + kb];
        acc[ct] = __builtin_amdgcn_mfma_f32_16x16x32_bf16(af, bfr, acc[ct], 0, 0, 0);
      }
    }
#pragma unroll
    for (int r = 0; r < 4; ++r) {
      const int row = 16 * w + hi4 * 4 + r;
      const int node = nbase + row;
      const float x0 = xt[row * 4 + 0], x1 = xt[row * 4 + 1],
                  x2 = xt[row * 4 + 2], x3 = xt[row * 4 + 3];
#pragma unroll
      for (int cg = 0; cg < 4; ++cg) {
        const int hc = 16 * cg + c15;
        float gr = bir[0][cg] + x0 * wir[0][cg][0] + x1 * wir[0][cg][1]
                 + x2 * wir[0][cg][2] + x3 * wir[0][cg][3] + acc[cg][r];
        float gz = bir[1][cg] + x0 * wir[1][cg][0] + x1 * wir[1][cg][1]
                 + x2 * wir[1][cg][2] + x3 * wir[1][cg][3] + acc[4 + cg][r];
        float gn = bir[2][cg] + x0 * wir[2][cg][0] + x1 * wir[2][cg][1]
                 + x2 * wir[2][cg][2] + x3 * wir[2][cg][3];
        float rg = 1.f / (1.f + __expf(-gr));
        float zg = 1.f / (1.f + __expf(-gz));
        float cold = carryF[row * 65 + hc];
        float ng = tanhf(gn + rg * (acc[8 + cg][r] + bhnr[cg]));
        float nc = (1.f - zg) * ng + zg * cold;
        hs[((t * B_ + b) * N_ + node) * H_ + hc] = f2b(nc);
        if (t == T_ - 1) hfin[(b * N_ + node) * H_ + hc] = nc;
        carryF[row * 65 + hc] = nc;
        carry[row * STR + hc] = (short)f2b(nc);
      }
    }
    __syncthreads();
  }
}

// ---------------------------------------------------------------------------
// Kernel 2: fused factor attention v2, ALL t in one launch.
// Block = one chunk of 16 factors; loops 16 (t,b) slices reusing weights/idxs.
// B-fragments live in registers (each wave's tiles share one col-tile ct=w);
// A/o in frag-major LDS (conflict-free b128); qkv stride-68; softmax on all
// 256 threads as (f,head,dq) with shuffle reduction; gather prefetched.
// ---------------------------------------------------------------------------
__global__ __launch_bounds__(256, 3) void k_attn(
    const unsigned short* __restrict__ hs,    // [T*B,N,H] bf16
    const int* __restrict__ indices,
    const float* __restrict__ Wq, const float* __restrict__ bq,
    const float* __restrict__ Wk, const float* __restrict__ bk,
    const float* __restrict__ Wv, const float* __restrict__ bv,
    const float* __restrict__ Wo, const float* __restrict__ bo,
    float* __restrict__ y)                    // [T*B,N,H] f32, pre-zeroed
{
  __shared__ unsigned short bufrag[3072];     // A/o frags: [rt*2+ks][lane*8+j]
  __shared__ unsigned short qkvs[9792];       // 3 x 48 x 68 (stride 68 u16)
  __shared__ float biasf[4][64];
  __shared__ int idxs[48];

  const int tid = threadIdx.x;
  const int lane = tid & 63;
  const int w = tid >> 6;
  const int c15 = lane & 15;
  const int hi4 = lane >> 4;
  const int bid = blockIdx.x;
  const int col = 16 * w + c15;               // this wave's column ownership

  if (tid < 48) idxs[tid] = indices[bid * 48 + tid];
  if (tid < 64) {
    biasf[0][tid] = bq[tid];
    biasf[1][tid] = bk[tid];
    biasf[2][tid] = bv[tid];
    biasf[3][tid] = bo[tid];
  }

  // per-wave B fragments in registers: QKV (m,ks) + Wo (ks), all at col-tile w
  s16x8 wB[3][2], wB3[2];
#pragma unroll
  for (int m = 0; m < 3; ++m) {
    const float* Wm = (m == 0) ? Wq : (m == 1) ? Wk : Wv;
#pragma unroll
    for (int ks = 0; ks < 2; ++ks) {
      union { s16x8 v; short s[8]; } u;
#pragma unroll
      for (int j = 0; j < 8; ++j)
        u.s[j] = (short)f2b(Wm[(ks * 32 + hi4 * 8 + j) * 64 + col]);
      wB[m][ks] = u.v;
    }
  }
#pragma unroll
  for (int ks = 0; ks < 2; ++ks) {
    union { s16x8 v; short s[8]; } u;
#pragma unroll
    for (int j = 0; j < 8; ++j)
      u.s[j] = (short)f2b(Wo[(ks * 32 + hi4 * 8 + j) * 64 + col]);
    wB3[ks] = u.v;
  }
  __syncthreads();

  // prefetch gather for it=0 (rows w,w+4,..,w+44; col = lane)
  unsigned short pf[12];
#pragma unroll
  for (int k = 0; k < 12; ++k)
    pf[k] = hs[(size_t)(idxs[w + 4 * k]) * H_ + lane];

  for (int it = 0; it < 16; ++it) {
    __syncthreads();                          // B0: prev Wo reads done
#pragma unroll
    for (int k = 0; k < 12; ++k) {            // write gathered g in A-frag layout
      int row = w + 4 * k;
      int rt = row >> 4, cr = row & 15;
      int ks = lane >> 5, h5 = (lane & 31) >> 3, j = lane & 7;
      bufrag[((rt * 2 + ks) << 9) + ((h5 * 16 + cr) << 3) + j] = pf[k];
    }
    __syncthreads();                          // B1

    // ---- QKV projections (per wave: 3 m x 3 rt tiles at ct=w) ----
    s16x8 afr[3][2];
#pragma unroll
    for (int rt = 0; rt < 3; ++rt)
#pragma unroll
      for (int ks = 0; ks < 2; ++ks)
        afr[rt][ks] = *(const s16x8*)&bufrag[((rt * 2 + ks) << 9) + (lane << 3)];
#pragma unroll
    for (int m = 0; m < 3; ++m) {
      float bias = biasf[m][col];
      float scl = (m == 0) ? 0.25f : 1.f;     // 1/sqrt(HD) folded into q
#pragma unroll
      for (int rt = 0; rt < 3; ++rt) {
        f32x4 acc = (f32x4){0.f, 0.f, 0.f, 0.f};
        acc = __builtin_amdgcn_mfma_f32_16x16x32_bf16(afr[rt][0], wB[m][0], acc, 0, 0, 0);
        acc = __builtin_amdgcn_mfma_f32_16x16x32_bf16(afr[rt][1], wB[m][1], acc, 0, 0, 0);
#pragma unroll
        for (int r = 0; r < 4; ++r) {
          int row = 16 * rt + hi4 * 4 + r;
          qkvs[m * 3264 + row * 68 + col] = f2b((acc[r] + bias) * scl);
        }
      }
    }
    // prefetch next (t,b) slice while qkv settles
    if (it < 15) {
      const size_t base = (size_t)(it + 1) * N_;
#pragma unroll
      for (int k = 0; k < 12; ++k)
        pf[k] = hs[(base + idxs[w + 4 * k]) * H_ + lane];
    }
    __syncthreads();                          // B2

    // ---- softmax + PV: thread = (f, head, dq); b64 LDS reads ----
    {
      int f = tid >> 4, head = (tid >> 2) & 3, dq = tid & 3;
      int colb = head * 16 + dq * 4;
      float qv[3][4], kv[3][4], vv[3][4];
#pragma unroll
      for (int qi = 0; qi < 3; ++qi) {
        int base = (3 * f + qi) * 68 + colb;
        unsigned long long uq = *(const unsigned long long*)&qkvs[base];
        unsigned long long uk = *(const unsigned long long*)&qkvs[3264 + base];
        unsigned long long uv = *(const unsigned long long*)&qkvs[6528 + base];
#pragma unroll
        for (int e = 0; e < 4; ++e) {
          qv[qi][e] = b2f((unsigned short)(uq >> (16 * e)));
          kv[qi][e] = b2f((unsigned short)(uk >> (16 * e)));
          vv[qi][e] = b2f((unsigned short)(uv >> (16 * e)));
        }
      }
      float s[3][3];
#pragma unroll
      for (int qi = 0; qi < 3; ++qi)
#pragma unroll
        for (int ki = 0; ki < 3; ++ki) {
          float a = qv[qi][0] * kv[ki][0] + qv[qi][1] * kv[ki][1]
                  + qv[qi][2] * kv[ki][2] + qv[qi][3] * kv[ki][3];
          a += __shfl_xor(a, 1, 64);
          a += __shfl_xor(a, 2, 64);
          s[qi][ki] = a;
        }
#pragma unroll
      for (int qi = 0; qi < 3; ++qi) {
        float mx = fmaxf(s[qi][0], fmaxf(s[qi][1], s[qi][2]));
        float e0 = __expf(s[qi][0] - mx), e1 = __expf(s[qi][1] - mx), e2 = __expf(s[qi][2] - mx);
        float inv = 1.f / (e0 + e1 + e2);
        e0 *= inv; e1 *= inv; e2 *= inv;
        int row = 3 * f + qi;
        int rt = row >> 4, cr = row & 15;
#pragma unroll
        for (int e = 0; e < 4; ++e) {
          float o = e0 * vv[0][e] + e1 * vv[1][e] + e2 * vv[2][e];
          int h = colb + e;
          int ks = h >> 5, h5 = (h & 31) >> 3, j = h & 7;
          bufrag[((rt * 2 + ks) << 9) + ((h5 * 16 + cr) << 3) + j] = f2b(o);
        }
      }
    }
    __syncthreads();                          // B3

    // ---- a = o @ Wo + bo, scatter via f32 atomics ----
    {
      const float bo_ = biasf[3][col];
      const int tb = it;
#pragma unroll
      for (int rt = 0; rt < 3; ++rt) {
        s16x8 o0 = *(const s16x8*)&bufrag[((rt * 2 + 0) << 9) + (lane << 3)];
        s16x8 o1 = *(const s16x8*)&bufrag[((rt * 2 + 1) << 9) + (lane << 3)];
        f32x4 acc = (f32x4){0.f, 0.f, 0.f, 0.f};
        acc = __builtin_amdgcn_mfma_f32_16x16x32_bf16(o0, wB3[0], acc, 0, 0, 0);
        acc = __builtin_amdgcn_mfma_f32_16x16x32_bf16(o1, wB3[1], acc, 0, 0, 0);
#pragma unroll
        for (int r = 0; r < 4; ++r) {
          int row = 16 * rt + hi4 * 4 + r;
          atomicAdd(&y[(tb * N_ + idxs[row]) * H_ + col], acc[r] + bo_);
        }
      }
    }
  }
}

// ---------------------------------------------------------------------------
// Kernel 3: ALL t: y/=nnz; logit MLP via MFMA; y_global partial sums.
// Grid 4096 = 16 tb x 256 blocks of 64 nodes.
// ---------------------------------------------------------------------------
__global__ __launch_bounds__(256) void k_head(
    const float* __restrict__ y,              // [T*B,N,H] f32
    const float* __restrict__ nnz,
    const float* __restrict__ extra,
    const float* __restrict__ W1, const float* __restrict__ b1,
    const float* __restrict__ W2, const float* __restrict__ b2,
    float* __restrict__ yg,                   // [T*B,KALL,H] f32, pre-zeroed
    float* __restrict__ logit)                // [T,B,N] f32
{
  __shared__ short w1T[64 * STR];
  __shared__ short arow[64 * STR];
  __shared__ float hEx[64];
  __shared__ float w2s[64];
  __shared__ float red[4][64];

  const int tid = threadIdx.x;
  const int lane = tid & 63;
  const int w = tid >> 6;
  const int c15 = lane & 15;
  const int hi4 = lane >> 4;
  const int bid = blockIdx.x;
  const int tb = bid >> 8;             // 0..15
  const int nbase = (bid & 255) * 64;
  const int kall = nbase >> 12;

  for (int i = tid; i < 4096; i += 256) {
    int k = i >> 6, colc = i & 63;
    w1T[colc * STR + k] = (short)f2b(W1[i]);
  }
  if (tid < 64) {
    float s = b1[tid];
#pragma unroll
    for (int e = 0; e < 4; ++e)
      s += extra[(tb * KALL_ + kall) * DE_ + e] * W1[(64 + e) * 64 + tid];
    hEx[tid] = s;
    w2s[tid] = W2[tid];
  }
  float accp = 0.f;
  for (int i = tid; i < 4096; i += 256) {
    int r = i >> 6, hcol = i & 63;
    int node = nbase + r;
    float val = y[(tb * N_ + node) * H_ + hcol] / nnz[node];
    accp += val;
    arow[r * STR + hcol] = (short)f2b(val);
  }
  red[w][lane] = accp;
  __syncthreads();

  f32x4 acc[4];
#pragma unroll
  for (int ct = 0; ct < 4; ++ct) acc[ct] = (f32x4){0.f, 0.f, 0.f, 0.f};
#pragma unroll
  for (int ks = 0; ks < 2; ++ks) {
    int kb = ks * 32 + hi4 * 8;
    s16x8 af = *(const s16x8*)&arow[(16 * w + c15) * STR + kb];
#pragma unroll
    for (int ct = 0; ct < 4; ++ct) {
      s16x8 bfr = *(const s16x8*)&w1T[(16 * ct + c15) * STR + kb];
      acc[ct] = __builtin_amdgcn_mfma_f32_16x16x32_bf16(af, bfr, acc[ct], 0, 0, 0);
    }
  }
  const float b2v = b2[0];
#pragma unroll
  for (int r = 0; r < 4; ++r) {
    float s = 0.f;
#pragma unroll
    for (int ct = 0; ct < 4; ++ct) {
      int colc = 16 * ct + c15;
      s += fmaxf(acc[ct][r] + hEx[colc], 0.f) * w2s[colc];
    }
    s += __shfl_xor(s, 1, 64);
    s += __shfl_xor(s, 2, 64);
    s += __shfl_xor(s, 4, 64);
    s += __shfl_xor(s, 8, 64);
    if (c15 == 0)
      logit[tb * N_ + nbase + 16 * w + hi4 * 4 + r] = s + b2v;
  }
  if (tid < 64) {
    float sv = red[0][tid] + red[1][tid] + red[2][tid] + red[3][tid];
    atomicAdd(&yg[(tb * KALL_ + kall) * H_ + tid], sv);
  }
}

// ---------------------------------------------------------------------------
// Kernel 4: value head + h_global passthrough (f32)
// ---------------------------------------------------------------------------
__global__ __launch_bounds__(256) void k_final(
    const float* __restrict__ yg,
    const float* __restrict__ extra,
    const float* __restrict__ Wv1, const float* __restrict__ bv1,
    const float* __restrict__ hg_in,
    float* __restrict__ value_out,
    float* __restrict__ hg_out)
{
  const int tid = threadIdx.x;
  if (tid < 16) {
    const float bv = bv1[0];
    float v = 0.f;
    for (int kall = 0; kall < 4; ++kall) {
      float s = bv;
      for (int hh = 0; hh < 64; ++hh)
        s += (yg[(tid * KALL_ + kall) * H_ + hh] * (1.f / 4096.f)) * Wv1[hh];
      for (int e = 0; e < 4; ++e)
        s += extra[(tid * KALL_ + kall) * DE_ + e] * Wv1[64 + e];
      v += s;
    }
    value_out[tid] = v;
  }
  for (int i = tid; i < 1024; i += 256) hg_out[i] = hg_in[i];
}

// ---------------------------------------------------------------------------
// Workspace layout (100.66 MB — proven safe by R3/R4 bit-identity across
// 100 MB vs 32 MB layouts):
//   yg @ 0        : 16,384 B     f32 [T*B,KALL,H]
//   y  @ 16384    : 67,108,864 B f32 [T*B,N,H]
//   hs @ 67125248 : 33,554,432 B bf16 [T*B,N,H]
// ---------------------------------------------------------------------------
extern "C" void kernel_launch(void* const* d_in, const int* in_sizes, int n_in,
                              void* d_out, int out_size, void* d_ws, size_t ws_size,
                              hipStream_t stream)
{
  (void)in_sizes; (void)n_in; (void)out_size; (void)ws_size;
  const float* h0    = (const float*)d_in[0];
  const float* hg    = (const float*)d_in[1];
  const float* x     = (const float*)d_in[2];
  const float* extra = (const float*)d_in[3];
  const int*   dn    = (const int*)d_in[4];
  const int*   idx   = (const int*)d_in[5];
  const float* nnz   = (const float*)d_in[6];
  const float* Wi    = (const float*)d_in[7];
  const float* bi    = (const float*)d_in[8];
  const float* Wh    = (const float*)d_in[9];
  const float* bhn   = (const float*)d_in[10];
  const float* Wq    = (const float*)d_in[11];
  const float* bq    = (const float*)d_in[12];
  const float* Wk    = (const float*)d_in[13];
  const float* bk    = (const float*)d_in[14];
  const float* Wv    = (const float*)d_in[15];
  const float* bv    = (const float*)d_in[16];
  const float* Wo    = (const float*)d_in[17];
  const float* bo    = (const float*)d_in[18];
  const float* W1    = (const float*)d_in[19];
  const float* b1    = (const float*)d_in[20];
  const float* W2    = (const float*)d_in[21];
  const float* b2    = (const float*)d_in[22];
  const float* Wv1   = (const float*)d_in[23];
  const float* bv1   = (const float*)d_in[24];

  float* out = (float*)d_out;
  float* out_hfin  = out;                 // [B,N,H]    4194304
  float* out_hg    = out + 4194304;       // [B,K,DOUT]    1024
  float* out_logit = out + 4195328;       // [T,B,N]     262144
  float* out_value = out + 4457472;       // [T,B]           16

  char* wsb = (char*)d_ws;
  float*          yg = (float*)wsb;                       // 16 KB
  float*          y  = (float*)(wsb + 16384);             // 64 MB
  unsigned short* hs = (unsigned short*)(wsb + 67125248); // 32 MB

  hipMemsetAsync(wsb, 0, 16384 + 67108864, stream);       // yg + y
  k_gru <<<1024, 256, 0, stream>>>(h0, x, dn, Wi, bi, Wh, bhn, hs, out_hfin);
  k_attn<<<1024, 256, 0, stream>>>(hs, idx, Wq, bq, Wk, bk, Wv, bv, Wo, bo, y);
  k_head<<<4096, 256, 0, stream>>>(y, nnz, extra, W1, b1, W2, b2, yg, out_logit);
  k_final<<<1, 256, 0, stream>>>(yg, extra, Wv1, bv1, hg, out_value, out_hg);
}

// Round 9
// 380.441 us; speedup vs baseline: 1.6434x; 1.0045x over previous
//
#include <hip/hip_runtime.h>
#include <hip/hip_bf16.h>

#define T_ 4
#define B_ 4
#define N_ 16384
#define KALL_ 4
#define F_ 16384
#define ORD_ 3
#define DIN_ 4
#define H_ 64
#define H3_ 192
#define DE_ 4
#define STR 72   // padded bf16 leading-dim for MFMA A/B LDS tiles
#define NE_ 49152  // F*ORD edges

typedef __attribute__((ext_vector_type(8))) short s16x8;
typedef __attribute__((ext_vector_type(4))) float f32x4;
typedef unsigned long long u64;

static __device__ __forceinline__ float b2f(unsigned short u) {
  union { unsigned u; float f; } x; x.u = ((unsigned)u) << 16; return x.f;
}
static __device__ __forceinline__ unsigned short f2b(float f) {
  __hip_bfloat16 h = __float2bfloat16(f);  // RNE
  union { __hip_bfloat16 h; unsigned short u; } x; x.h = h; return x.u;
}

// dones encoding sniffer (unchanged from passing R7/R8 kernels)
static __device__ __forceinline__ bool decode_done(const int* __restrict__ dn, int tb) {
  bool word = true;
#pragma unroll
  for (int i = 0; i < 16; ++i) {
    int v = dn[i];
    if (v != 0 && v != 1 && v != 0x3F800000) word = false;
  }
  if (word) return dn[tb] != 0;
  return ((const unsigned char*)dn)[tb] != 0;
}

// ---------------------------------------------------------------------------
// CSR build: inverse of indices[F,ORD] -> per-node edge lists. 49152 entries.
// ---------------------------------------------------------------------------
__global__ __launch_bounds__(256) void k_csr_count(
    const int* __restrict__ idx, int* __restrict__ cnt) {
  int e = blockIdx.x * 256 + threadIdx.x;
  if (e < NE_) atomicAdd(&cnt[idx[e]], 1);
}
__global__ __launch_bounds__(256) void k_csr_scan(
    const int* __restrict__ cnt, int* __restrict__ offs, int* __restrict__ cursor) {
  __shared__ int part[256];
  __shared__ int base[256];
  int t = threadIdx.x;
  int s = 0;
  for (int j = 0; j < 64; ++j) s += cnt[t * 64 + j];
  part[t] = s;
  __syncthreads();
  if (t == 0) {
    int run = 0;
    for (int i = 0; i < 256; ++i) { base[i] = run; run += part[i]; }
  }
  __syncthreads();
  int run = base[t];
  for (int j = 0; j < 64; ++j) {
    offs[t * 64 + j] = run;
    cursor[t * 64 + j] = run;
    run += cnt[t * 64 + j];
  }
  if (t == 255) offs[N_] = run;
}
__global__ __launch_bounds__(256) void k_csr_fill(
    const int* __restrict__ idx, int* __restrict__ cursor, int* __restrict__ elist) {
  int e = blockIdx.x * 256 + threadIdx.x;
  if (e < NE_) {
    int pos = atomicAdd(&cursor[idx[e]], 1);
    elist[pos] = e;
  }
}

// ---------------------------------------------------------------------------
// Kernel 1: GRU, all t in one launch (unchanged from R8 — passing).
// ---------------------------------------------------------------------------
__global__ __launch_bounds__(256) void k_gru(
    const float* __restrict__ h0,
    const float* __restrict__ x,
    const int* __restrict__ dones,
    const float* __restrict__ Wi,
    const float* __restrict__ bi,
    const float* __restrict__ Wh,
    const float* __restrict__ bhn,
    unsigned short* __restrict__ hs,     // [T*B,N,H] bf16
    float* __restrict__ hfin)            // [B,N,H] f32
{
  __shared__ short whT[H3_ * STR];
  __shared__ float carryF[H_ * 65];
  __shared__ short carry[H_ * STR];
  __shared__ float xt[256];

  const int tid = threadIdx.x;
  const int lane = tid & 63;
  const int w = tid >> 6;
  const int c15 = lane & 15;
  const int hi4 = lane >> 4;
  const int bid = blockIdx.x;
  const int b = bid >> 8;
  const int nbase = (bid & 255) * 64;

  for (int i = tid; i < H_ * H3_; i += 256) {
    int k = i / H3_;
    int c = i - k * H3_;
    whT[c * STR + k] = (short)f2b(Wh[i]);
  }
  for (int i = tid; i < H_ * H_; i += 256) {
    int r = i >> 6, k = i & 63;
    float v = h0[(b * N_ + nbase + r) * H_ + k];
    carryF[r * 65 + k] = v;
    carry[r * STR + k] = (short)f2b(v);
  }

  float wir[3][4][4], bir[3][4], bhnr[4];
#pragma unroll
  for (int cg = 0; cg < 4; ++cg) {
    int hc = 16 * cg + c15;
    bhnr[cg] = bhn[hc];
#pragma unroll
    for (int g = 0; g < 3; ++g) {
      bir[g][cg] = bi[g * 64 + hc];
#pragma unroll
      for (int kk = 0; kk < 4; ++kk)
        wir[g][cg][kk] = Wi[kk * H3_ + g * 64 + hc];
    }
  }
  __syncthreads();

  for (int t = 0; t < T_; ++t) {
    xt[tid] = x[((t * B_ + b) * N_ + nbase + (tid >> 2)) * DIN_ + (tid & 3)];
    if (decode_done(dones, t * B_ + b)) {
      for (int i = tid; i < H_ * 65; i += 256) carryF[i] = 0.f;
      for (int i = tid; i < H_ * STR; i += 256) carry[i] = 0;
    }
    __syncthreads();

    f32x4 acc[12];
#pragma unroll
    for (int ct = 0; ct < 12; ++ct) acc[ct] = (f32x4){0.f, 0.f, 0.f, 0.f};
    const int rowA = 16 * w + c15;
#pragma unroll
    for (int ks = 0; ks < 2; ++ks) {
      const int kb = ks * 32 + hi4 * 8;
      s16x8 af = *(const s16x8*)&carry[rowA * STR + kb];
#pragma unroll
      for (int ct = 0; ct < 12; ++ct) {
        s16x8 bfr = *(const s16x8*)&whT[(16 * ct + c15) * STR + kb];
        acc[ct] = __builtin_amdgcn_mfma_f32_16x16x32_bf16(af, bfr, acc[ct], 0, 0, 0);
      }
    }
#pragma unroll
    for (int r = 0; r < 4; ++r) {
      const int row = 16 * w + hi4 * 4 + r;
      const int node = nbase + row;
      const float x0 = xt[row * 4 + 0], x1 = xt[row * 4 + 1],
                  x2 = xt[row * 4 + 2], x3 = xt[row * 4 + 3];
#pragma unroll
      for (int cg = 0; cg < 4; ++cg) {
        const int hc = 16 * cg + c15;
        float gr = bir[0][cg] + x0 * wir[0][cg][0] + x1 * wir[0][cg][1]
                 + x2 * wir[0][cg][2] + x3 * wir[0][cg][3] + acc[cg][r];
        float gz = bir[1][cg] + x0 * wir[1][cg][0] + x1 * wir[1][cg][1]
                 + x2 * wir[1][cg][2] + x3 * wir[1][cg][3] + acc[4 + cg][r];
        float gn = bir[2][cg] + x0 * wir[2][cg][0] + x1 * wir[2][cg][1]
                 + x2 * wir[2][cg][2] + x3 * wir[2][cg][3];
        float rg = 1.f / (1.f + __expf(-gr));
        float zg = 1.f / (1.f + __expf(-gz));
        float cold = carryF[row * 65 + hc];
        float ng = tanhf(gn + rg * (acc[8 + cg][r] + bhnr[cg]));
        float nc = (1.f - zg) * ng + zg * cold;
        hs[((t * B_ + b) * N_ + node) * H_ + hc] = f2b(nc);
        if (t == T_ - 1) hfin[(b * N_ + node) * H_ + hc] = nc;
        carryF[row * 65 + hc] = nc;
        carry[row * STR + hc] = (short)f2b(nc);
      }
    }
    __syncthreads();
  }
}

// ---------------------------------------------------------------------------
// Kernel 2: fused factor attention v3 — NO atomics. Block = chunk of 16
// factors, loops 8 (t,b) slices (one half). Per-edge output a=o@Wo+bo written
// as coalesced bf16 rows into a_edge. Gather via u64 loads; frag stores
// XOR-swizzled (cr^=h5<<2) so write banks spread 4 -> 32.
// ---------------------------------------------------------------------------
__global__ __launch_bounds__(256, 3) void k_attn(
    const int tb0,
    const unsigned short* __restrict__ hs,    // [T*B,N,H] bf16
    const int* __restrict__ indices,
    const float* __restrict__ Wq, const float* __restrict__ bq,
    const float* __restrict__ Wk, const float* __restrict__ bk,
    const float* __restrict__ Wv, const float* __restrict__ bv,
    const float* __restrict__ Wo, const float* __restrict__ bo,
    unsigned short* __restrict__ a_edge)      // [8,NE,H] bf16
{
  __shared__ __align__(16) unsigned short bufrag[3072]; // A/o frags (swizzled)
  __shared__ __align__(8)  unsigned short qkvs[9792];   // 3 x 48 x 68
  __shared__ float biasf[4][64];
  __shared__ int idxs[48];

  const int tid = threadIdx.x;
  const int lane = tid & 63;
  const int w = tid >> 6;
  const int c15 = lane & 15;
  const int hi4 = lane >> 4;
  const int bid = blockIdx.x;
  const int col = 16 * w + c15;
  const int swz = (c15 ^ (hi4 << 2));         // swizzled frag-read row

  if (tid < 48) idxs[tid] = indices[bid * 48 + tid];
  if (tid < 64) {
    biasf[0][tid] = bq[tid];
    biasf[1][tid] = bk[tid];
    biasf[2][tid] = bv[tid];
    biasf[3][tid] = bo[tid];
  }

  // per-wave B fragments in registers (all tiles share col-tile ct=w)
  s16x8 wB[3][2], wB3[2];
#pragma unroll
  for (int m = 0; m < 3; ++m) {
    const float* Wm = (m == 0) ? Wq : (m == 1) ? Wk : Wv;
#pragma unroll
    for (int ks = 0; ks < 2; ++ks) {
      union { s16x8 v; short s[8]; } u;
#pragma unroll
      for (int j = 0; j < 8; ++j)
        u.s[j] = (short)f2b(Wm[(ks * 32 + hi4 * 8 + j) * 64 + col]);
      wB[m][ks] = u.v;
    }
  }
#pragma unroll
  for (int ks = 0; ks < 2; ++ks) {
    union { s16x8 v; short s[8]; } u;
#pragma unroll
    for (int j = 0; j < 8; ++j)
      u.s[j] = (short)f2b(Wo[(ks * 32 + hi4 * 8 + j) * 64 + col]);
    wB3[ks] = u.v;
  }
  __syncthreads();

  // prefetch gather for it=0: thread covers (row=idx>>4, g=idx&15), u64 each
  u64 pf[3];
#pragma unroll
  for (int k = 0; k < 3; ++k) {
    int idx = k * 256 + tid, row = idx >> 4, g = idx & 15;
    pf[k] = *(const u64*)&hs[((size_t)tb0 * N_ + idxs[row]) * H_ + g * 4];
  }

  for (int it = 0; it < 8; ++it) {
    __syncthreads();                          // B0: prev Wo reads done
#pragma unroll
    for (int k = 0; k < 3; ++k) {             // swizzled frag-layout store
      int idx = k * 256 + tid, row = idx >> 4, g = idx & 15;
      int rt = row >> 4, cr = row & 15;
      int ks = g >> 3, h5 = (g >> 1) & 3, j = (g & 1) * 4;
      int cr2 = cr ^ (h5 << 2);
      *(u64*)&bufrag[((rt * 2 + ks) << 9) + ((h5 * 16 + cr2) << 3) + j] = pf[k];
    }
    __syncthreads();                          // B1

    // ---- QKV projections (per wave: 3 m x 3 rt tiles at ct=w) ----
    s16x8 afr[3][2];
#pragma unroll
    for (int rt = 0; rt < 3; ++rt)
#pragma unroll
      for (int ks = 0; ks < 2; ++ks)
        afr[rt][ks] = *(const s16x8*)&bufrag[((rt * 2 + ks) << 9) + ((hi4 * 16 + swz) << 3)];
#pragma unroll
    for (int m = 0; m < 3; ++m) {
      float bias = biasf[m][col];
      float scl = (m == 0) ? 0.25f : 1.f;     // 1/sqrt(HD) folded into q
#pragma unroll
      for (int rt = 0; rt < 3; ++rt) {
        f32x4 acc = (f32x4){0.f, 0.f, 0.f, 0.f};
        acc = __builtin_amdgcn_mfma_f32_16x16x32_bf16(afr[rt][0], wB[m][0], acc, 0, 0, 0);
        acc = __builtin_amdgcn_mfma_f32_16x16x32_bf16(afr[rt][1], wB[m][1], acc, 0, 0, 0);
#pragma unroll
        for (int r = 0; r < 4; ++r) {
          int row = 16 * rt + hi4 * 4 + r;
          qkvs[m * 3264 + row * 68 + col] = f2b((acc[r] + bias) * scl);
        }
      }
    }
    // prefetch next slice
    if (it < 7) {
      const size_t base = (size_t)(tb0 + it + 1) * N_;
#pragma unroll
      for (int k = 0; k < 3; ++k) {
        int idx = k * 256 + tid, row = idx >> 4, g = idx & 15;
        pf[k] = *(const u64*)&hs[(base + idxs[row]) * H_ + g * 4];
      }
    }
    __syncthreads();                          // B2

    // ---- softmax + PV: thread = (f, head, dq); b64 LDS reads ----
    {
      int f = tid >> 4, head = (tid >> 2) & 3, dq = tid & 3;
      int colb = head * 16 + dq * 4;
      float qv[3][4], kv[3][4], vv[3][4];
#pragma unroll
      for (int qi = 0; qi < 3; ++qi) {
        int base = (3 * f + qi) * 68 + colb;
        u64 uq = *(const u64*)&qkvs[base];
        u64 uk = *(const u64*)&qkvs[3264 + base];
        u64 uv = *(const u64*)&qkvs[6528 + base];
#pragma unroll
        for (int e = 0; e < 4; ++e) {
          qv[qi][e] = b2f((unsigned short)(uq >> (16 * e)));
          kv[qi][e] = b2f((unsigned short)(uk >> (16 * e)));
          vv[qi][e] = b2f((unsigned short)(uv >> (16 * e)));
        }
      }
      float s[3][3];
#pragma unroll
      for (int qi = 0; qi < 3; ++qi)
#pragma unroll
        for (int ki = 0; ki < 3; ++ki) {
          float a = qv[qi][0] * kv[ki][0] + qv[qi][1] * kv[ki][1]
                  + qv[qi][2] * kv[ki][2] + qv[qi][3] * kv[ki][3];
          a += __shfl_xor(a, 1, 64);
          a += __shfl_xor(a, 2, 64);
          s[qi][ki] = a;
        }
      const int ks2 = colb >> 5, h5b = (colb >> 3) & 3, jb = colb & 7;
#pragma unroll
      for (int qi = 0; qi < 3; ++qi) {
        float mx = fmaxf(s[qi][0], fmaxf(s[qi][1], s[qi][2]));
        float e0 = __expf(s[qi][0] - mx), e1 = __expf(s[qi][1] - mx), e2 = __expf(s[qi][2] - mx);
        float inv = 1.f / (e0 + e1 + e2);
        e0 *= inv; e1 *= inv; e2 *= inv;
        int row = 3 * f + qi;
        int rt = row >> 4, cr2 = (row & 15) ^ (h5b << 2);
        u64 pack = 0;
#pragma unroll
        for (int e = 0; e < 4; ++e) {
          float o = e0 * vv[0][e] + e1 * vv[1][e] + e2 * vv[2][e];
          pack |= (u64)f2b(o) << (16 * e);
        }
        *(u64*)&bufrag[((rt * 2 + ks2) << 9) + ((h5b * 16 + cr2) << 3) + jb] = pack;
      }
    }
    __syncthreads();                          // B3

    // ---- a = o @ Wo + bo, coalesced bf16 store (NO atomics) ----
    {
      const float bo_ = biasf[3][col];
      const size_t abase = (size_t)it * NE_ + (size_t)bid * 48;
#pragma unroll
      for (int rt = 0; rt < 3; ++rt) {
        s16x8 o0 = *(const s16x8*)&bufrag[((rt * 2 + 0) << 9) + ((hi4 * 16 + swz) << 3)];
        s16x8 o1 = *(const s16x8*)&bufrag[((rt * 2 + 1) << 9) + ((hi4 * 16 + swz) << 3)];
        f32x4 acc = (f32x4){0.f, 0.f, 0.f, 0.f};
        acc = __builtin_amdgcn_mfma_f32_16x16x32_bf16(o0, wB3[0], acc, 0, 0, 0);
        acc = __builtin_amdgcn_mfma_f32_16x16x32_bf16(o1, wB3[1], acc, 0, 0, 0);
#pragma unroll
        for (int r = 0; r < 4; ++r) {
          int row = 16 * rt + hi4 * 4 + r;
          a_edge[(abase + row) * H_ + col] = f2b(acc[r] + bo_);
        }
      }
    }
  }
}

// ---------------------------------------------------------------------------
// Kernel 3: one half (8 tb): per-node CSR gather-sum of a_edge, /nnz, logit
// MLP via MFMA, y_global partial sums. Grid 2048 = 8 ls x 256.
// ---------------------------------------------------------------------------
__global__ __launch_bounds__(256) void k_head(
    const int tb0,
    const unsigned short* __restrict__ a_edge, // [8,NE,H] bf16
    const int* __restrict__ offs, const int* __restrict__ elist,
    const float* __restrict__ nnz,
    const float* __restrict__ extra,
    const float* __restrict__ W1, const float* __restrict__ b1,
    const float* __restrict__ W2, const float* __restrict__ b2,
    float* __restrict__ yg,                    // [T*B,KALL,H] f32, pre-zeroed
    float* __restrict__ logit)                 // [T,B,N] f32
{
  __shared__ short w1T[64 * STR];
  __shared__ short arow[64 * STR];
  __shared__ float hEx[64];
  __shared__ float w2s[64];
  __shared__ float red[4][64];

  const int tid = threadIdx.x;
  const int lane = tid & 63;
  const int w = tid >> 6;
  const int c15 = lane & 15;
  const int hi4 = lane >> 4;
  const int bid = blockIdx.x;
  const int ls = bid >> 8;             // local slice 0..7
  const int tb = tb0 + ls;
  const int nbase = (bid & 255) * 64;
  const int kall = nbase >> 12;

  for (int i = tid; i < 4096; i += 256) {
    int k = i >> 6, colc = i & 63;
    w1T[colc * STR + k] = (short)f2b(W1[i]);
  }
  if (tid < 64) {
    float s = b1[tid];
#pragma unroll
    for (int e = 0; e < 4; ++e)
      s += extra[(tb * KALL_ + kall) * DE_ + e] * W1[(64 + e) * 64 + tid];
    hEx[tid] = s;
    w2s[tid] = W2[tid];
  }
  const size_t ebase = (size_t)ls * NE_;
  float accp = 0.f;
  for (int i = tid; i < 4096; i += 256) {
    int r = i >> 6, hcol = i & 63;      // all 64 lanes share node -> coalesced
    int node = nbase + r;
    int beg = offs[node], end = offs[node + 1];
    float val = 0.f;
    for (int e = beg; e < end; ++e)
      val += b2f(a_edge[(ebase + elist[e]) * H_ + hcol]);
    val /= nnz[node];
    accp += val;
    arow[r * STR + hcol] = (short)f2b(val);
  }
  red[w][lane] = accp;
  __syncthreads();

  f32x4 acc[4];
#pragma unroll
  for (int ct = 0; ct < 4; ++ct) acc[ct] = (f32x4){0.f, 0.f, 0.f, 0.f};
#pragma unroll
  for (int ks = 0; ks < 2; ++ks) {
    int kb = ks * 32 + hi4 * 8;
    s16x8 af = *(const s16x8*)&arow[(16 * w + c15) * STR + kb];
#pragma unroll
    for (int ct = 0; ct < 4; ++ct) {
      s16x8 bfr = *(const s16x8*)&w1T[(16 * ct + c15) * STR + kb];
      acc[ct] = __builtin_amdgcn_mfma_f32_16x16x32_bf16(af, bfr, acc[ct], 0, 0, 0);
    }
  }
  const float b2v = b2[0];
#pragma unroll
  for (int r = 0; r < 4; ++r) {
    float s = 0.f;
#pragma unroll
    for (int ct = 0; ct < 4; ++ct) {
      int colc = 16 * ct + c15;
      s += fmaxf(acc[ct][r] + hEx[colc], 0.f) * w2s[colc];
    }
    s += __shfl_xor(s, 1, 64);
    s += __shfl_xor(s, 2, 64);
    s += __shfl_xor(s, 4, 64);
    s += __shfl_xor(s, 8, 64);
    if (c15 == 0)
      logit[tb * N_ + nbase + 16 * w + hi4 * 4 + r] = s + b2v;
  }
  if (tid < 64) {
    float sv = red[0][tid] + red[1][tid] + red[2][tid] + red[3][tid];
    atomicAdd(&yg[(tb * KALL_ + kall) * H_ + tid], sv);
  }
}

// ---------------------------------------------------------------------------
// Kernel 4: value head + h_global passthrough (f32)
// ---------------------------------------------------------------------------
__global__ __launch_bounds__(256) void k_final(
    const float* __restrict__ yg,
    const float* __restrict__ extra,
    const float* __restrict__ Wv1, const float* __restrict__ bv1,
    const float* __restrict__ hg_in,
    float* __restrict__ value_out,
    float* __restrict__ hg_out)
{
  const int tid = threadIdx.x;
  if (tid < 16) {
    const float bv = bv1[0];
    float v = 0.f;
    for (int kall = 0; kall < 4; ++kall) {
      float s = bv;
      for (int hh = 0; hh < 64; ++hh)
        s += (yg[(tid * KALL_ + kall) * H_ + hh] * (1.f / 4096.f)) * Wv1[hh];
      for (int e = 0; e < 4; ++e)
        s += extra[(tid * KALL_ + kall) * DE_ + e] * Wv1[64 + e];
      v += s;
    }
    value_out[tid] = v;
  }
  for (int i = tid; i < 1024; i += 256) hg_out[i] = hg_in[i];
}

// ---------------------------------------------------------------------------
// Workspace layout (84.4 MB < 100.7 MB proven safe in R8):
//   yg     @ 0        : 16,384 B    f32 [T*B,KALL,H]
//   cnt    @ 16384    : 65,536 B    int [N]
//   offs   @ 81920    : 65,540 B    int [N+1]
//   cursor @ 147584   : 65,536 B    int [N]
//   elist  @ 213120   : 196,608 B   int [NE]
//   hs     @ 524288   : 33,554,432 B bf16 [T*B,N,H]
//   a_edge @ 34078720 : 50,331,648 B bf16 [8,NE,H]  (reused per half)
// ---------------------------------------------------------------------------
extern "C" void kernel_launch(void* const* d_in, const int* in_sizes, int n_in,
                              void* d_out, int out_size, void* d_ws, size_t ws_size,
                              hipStream_t stream)
{
  (void)in_sizes; (void)n_in; (void)out_size; (void)ws_size;
  const float* h0    = (const float*)d_in[0];
  const float* hg    = (const float*)d_in[1];
  const float* x     = (const float*)d_in[2];
  const float* extra = (const float*)d_in[3];
  const int*   dn    = (const int*)d_in[4];
  const int*   idx   = (const int*)d_in[5];
  const float* nnz   = (const float*)d_in[6];
  const float* Wi    = (const float*)d_in[7];
  const float* bi    = (const float*)d_in[8];
  const float* Wh    = (const float*)d_in[9];
  const float* bhn   = (const float*)d_in[10];
  const float* Wq    = (const float*)d_in[11];
  const float* bq    = (const float*)d_in[12];
  const float* Wk    = (const float*)d_in[13];
  const float* bk    = (const float*)d_in[14];
  const float* Wv    = (const float*)d_in[15];
  const float* bv    = (const float*)d_in[16];
  const float* Wo    = (const float*)d_in[17];
  const float* bo    = (const float*)d_in[18];
  const float* W1    = (const float*)d_in[19];
  const float* b1    = (const float*)d_in[20];
  const float* W2    = (const float*)d_in[21];
  const float* b2    = (const float*)d_in[22];
  const float* Wv1   = (const float*)d_in[23];
  const float* bv1   = (const float*)d_in[24];

  float* out = (float*)d_out;
  float* out_hfin  = out;                 // [B,N,H]    4194304
  float* out_hg    = out + 4194304;       // [B,K,DOUT]    1024
  float* out_logit = out + 4195328;       // [T,B,N]     262144
  float* out_value = out + 4457472;       // [T,B]           16

  char* wsb = (char*)d_ws;
  float*          yg     = (float*)wsb;
  int*            cnt    = (int*)(wsb + 16384);
  int*            offs   = (int*)(wsb + 81920);
  int*            cursor = (int*)(wsb + 147584);
  int*            elist  = (int*)(wsb + 213120);
  unsigned short* hs     = (unsigned short*)(wsb + 524288);
  unsigned short* a_edge = (unsigned short*)(wsb + 34078720);

  hipMemsetAsync(wsb, 0, 81920, stream);      // yg + cnt
  k_csr_count<<<192, 256, 0, stream>>>(idx, cnt);
  k_csr_scan<<<1, 256, 0, stream>>>(cnt, offs, cursor);
  k_csr_fill<<<192, 256, 0, stream>>>(idx, cursor, elist);
  k_gru<<<1024, 256, 0, stream>>>(h0, x, dn, Wi, bi, Wh, bhn, hs, out_hfin);
  for (int half = 0; half < 2; ++half) {
    const int tb0 = half * 8;
    k_attn<<<1024, 256, 0, stream>>>(tb0, hs, idx, Wq, bq, Wk, bk, Wv, bv,
                                     Wo, bo, a_edge);
    k_head<<<2048, 256, 0, stream>>>(tb0, a_edge, offs, elist, nnz, extra,
                                     W1, b1, W2, b2, yg, out_logit);
  }
  k_final<<<1, 256, 0, stream>>>(yg, extra, Wv1, bv1, hg, out_value, out_hg);
}